// Round 4
// baseline (181.793 us; speedup 1.0000x reference)
//
#include <hip/hip_runtime.h>
#include <math.h>

#define DIMS 32
#define NROWS 4096
#define MROWS 8192
#define HID 100
#define TS 128
#define LDK 132  // padded K-major row stride (floats); 132*4=528 B, 16B-aligned

#define L2E 1.44269504088896340736f

typedef float f32x4 __attribute__((ext_vector_type(4)));

__device__ __forceinline__ float tanh_fast(float x) {
    float xc = fminf(fmaxf(x, -10.0f), 10.0f);
    float e = __builtin_amdgcn_exp2f(xc * (2.0f * L2E));  // e^(2x)
    return (e - 1.0f) * __builtin_amdgcn_rcpf(e + 1.0f);
}

// ---------------- Kernel 1: all the small work, one launch ----------------
// 48 blocks x 256. EVERY block redundantly computes var over all centroids
// (512 KB L2-cached read per block — ~1 us total across the chip; removes the
// separate reduction kernel + its launch/dependency stall).
// Blocks 0..15 : redundantly compute M = W2@W1 in LDS (the two Linears collapse —
//                no nonlinearity between them), then per-thread row
//                loc_s[n] = s * tanh(c@M^T + b2) * c   (pre-scaled by s = log2e/var
//                so k_pair never needs var), and B[n] = -0.5*log2e*|loc|^2/var.
// Blocks 16..47: A[m] = -0.5*log2e*|x_m|^2/var - 16*log2(2*pi*var).
__global__ __launch_bounds__(256) void k_prep(const float* __restrict__ cent,
                                              const float* __restrict__ x,
                                              const float* __restrict__ W1,
                                              const float* __restrict__ W2,
                                              const float* __restrict__ b2,
                                              float* __restrict__ loc,
                                              float* __restrict__ A,
                                              float* __restrict__ B) {
    int t = threadIdx.x;

    // --- redundant per-block var reduction over all 131072 centroid floats ---
    const float4* c4 = (const float4*)cent;
    float s = 0.0f, q = 0.0f;
    #pragma unroll 8
    for (int i = 0; i < 128; i++) {
        float4 a = c4[i * 256 + t];
        s += a.x + a.y + a.z + a.w;
        q += a.x * a.x + a.y * a.y + a.z * a.z + a.w * a.w;
    }
    #pragma unroll
    for (int off = 32; off > 0; off >>= 1) {
        s += __shfl_down(s, off);
        q += __shfl_down(q, off);
    }
    __shared__ float red[8];
    int lane = t & 63, wid = t >> 6;
    if (lane == 0) { red[wid] = s; red[4 + wid] = q; }
    __syncthreads();
    float S = red[0] + red[1] + red[2] + red[3];
    float Q = red[4] + red[5] + red[6] + red[7];
    const float cnt = (float)(NROWS * DIMS);
    float var = (Q - S * S / cnt) / (cnt - 1.0f);
    float iv = 1.0f / var;
    const float hv = -0.5f * L2E * iv;   // multiplies squared norms
    const float sc = L2E * iv;           // dot-product scale, folded into loc

    if (blockIdx.x < 16) {
        __shared__ float w1s[HID * DIMS];
        __shared__ float w2s[DIMS * HID];
        __shared__ __align__(16) float ms[DIMS * DIMS];
        __shared__ float b2s[DIMS];
        for (int i = t; i < HID * DIMS; i += 256) { w1s[i] = W1[i]; w2s[i] = W2[i]; }
        if (t < DIMS) b2s[t] = b2[t];
        __syncthreads();
        // M[r][cc] = sum_j W2[r*100+j] * W1[j*32+cc]; 4 entries per thread
        #pragma unroll
        for (int o = 0; o < 4; o++) {
            int id = o * 256 + t;
            int r = id >> 5, cc = id & 31;
            float a = 0.0f;
            for (int j = 0; j < HID; j++) a += w2s[r * HID + j] * w1s[j * DIMS + cc];
            ms[id] = a;
        }
        __syncthreads();

        int n = blockIdx.x * 256 + t;  // 0..4095
        float c[DIMS];
        const float4* cr = (const float4*)(cent + (size_t)n * DIMS);
        #pragma unroll
        for (int i = 0; i < 8; i++) {
            float4 v = cr[i];
            c[4 * i] = v.x; c[4 * i + 1] = v.y; c[4 * i + 2] = v.z; c[4 * i + 3] = v.w;
        }
        float lr[DIMS];
        float lsq = 0.0f;
        #pragma unroll
        for (int d = 0; d < DIMS; d++) {
            const float4* mr = (const float4*)&ms[d * DIMS];
            float a0 = 0.f, a1 = 0.f, a2 = 0.f, a3 = 0.f;
            #pragma unroll
            for (int kk = 0; kk < 8; kk++) {
                float4 m = mr[kk];
                a0 += c[4 * kk] * m.x;
                a1 += c[4 * kk + 1] * m.y;
                a2 += c[4 * kk + 2] * m.z;
                a3 += c[4 * kk + 3] * m.w;
            }
            float v = tanh_fast((a0 + a1) + (a2 + a3) + b2s[d]) * c[d];
            lr[d] = v;          // unscaled for the norm
            lsq += v * v;
        }
        float4* lo = (float4*)(loc + (size_t)n * DIMS);
        #pragma unroll
        for (int i = 0; i < 8; i++)
            lo[i] = make_float4(sc * lr[4 * i], sc * lr[4 * i + 1],
                                sc * lr[4 * i + 2], sc * lr[4 * i + 3]);
        B[n] = hv * lsq;
    } else {
        int m = (blockIdx.x - 16) * 256 + t;  // 0..8191
        const float4* xr = (const float4*)(x + (size_t)m * DIMS);
        float xsq = 0.0f;
        #pragma unroll
        for (int i = 0; i < 8; i++) {
            float4 v = xr[i];
            xsq += v.x * v.x + v.y * v.y + v.z * v.z + v.w * v.w;
        }
        float C0 = -16.0f * log2f(2.0f * (float)M_PI * var);  // -0.5*D*log2(2*pi*var)
        A[m] = hv * xsq + C0;
    }
}

// ---------------- Kernel 2: pairwise exp tile ----------------
// out[m,n] = exp2(A_m + B_n + dot(loc_s[n], x_m))   (loc pre-scaled; no var here)
// 128x128 tile per block, 256 threads, 8x8 micro-tile, nontemporal f32x4 stores.
__global__ __launch_bounds__(256) void k_pair(const float* __restrict__ x,
                                              const float* __restrict__ loc,
                                              const float* __restrict__ A,
                                              const float* __restrict__ B,
                                              float* __restrict__ out) {
    __shared__ __align__(16) float xs[DIMS][LDK];  // [k][m_local]
    __shared__ __align__(16) float ls[DIMS][LDK];  // [k][n_local]
    __shared__ float As[TS];
    __shared__ float Bs[TS];

    int n0 = blockIdx.x * TS;
    int m0 = blockIdx.y * TS;
    int t = threadIdx.x;

    // Stage tiles, transposing to K-major. Each thread: one half-row (16 floats).
    // Scalar LDS writes land pairwise in the same bank (2-way = free, m136).
    {
        int ml = t >> 1;               // 0..127
        int kh = (t & 1) * 16;         // 0 or 16
        const float4* xr = (const float4*)(x + (size_t)(m0 + ml) * DIMS + kh);
        float4 v0 = xr[0], v1 = xr[1], v2 = xr[2], v3 = xr[3];
        float vv[16] = {v0.x, v0.y, v0.z, v0.w, v1.x, v1.y, v1.z, v1.w,
                        v2.x, v2.y, v2.z, v2.w, v3.x, v3.y, v3.z, v3.w};
        #pragma unroll
        for (int qq = 0; qq < 16; qq++) xs[kh + qq][ml] = vv[qq];

        const float4* lrp = (const float4*)(loc + (size_t)(n0 + ml) * DIMS + kh);
        float4 u0 = lrp[0], u1 = lrp[1], u2 = lrp[2], u3 = lrp[3];
        float uu[16] = {u0.x, u0.y, u0.z, u0.w, u1.x, u1.y, u1.z, u1.w,
                        u2.x, u2.y, u2.z, u2.w, u3.x, u3.y, u3.z, u3.w};
        #pragma unroll
        for (int qq = 0; qq < 16; qq++) ls[kh + qq][ml] = uu[qq];
    }
    if (t < TS) As[t] = A[m0 + t];
    else        Bs[t - TS] = B[n0 + t - TS];
    __syncthreads();

    int tx = t & 15;   // n groups: n_local = 4*tx+j and 64+4*tx+j
    int ty = t >> 4;   // m groups: m_local = 4*ty+i and 64+4*ty+i

    float acc[8][8];
    #pragma unroll
    for (int i = 0; i < 8; i++)
        #pragma unroll
        for (int j = 0; j < 8; j++) acc[i][j] = 0.0f;

    #pragma unroll 4
    for (int k = 0; k < DIMS; k++) {
        float4 xa = *(const float4*)&xs[k][4 * ty];
        float4 xb = *(const float4*)&xs[k][64 + 4 * ty];
        float4 la = *(const float4*)&ls[k][4 * tx];
        float4 lb = *(const float4*)&ls[k][64 + 4 * tx];
        float xm[8] = {xa.x, xa.y, xa.z, xa.w, xb.x, xb.y, xb.z, xb.w};
        float ln[8] = {la.x, la.y, la.z, la.w, lb.x, lb.y, lb.z, lb.w};
        #pragma unroll
        for (int i = 0; i < 8; i++)
            #pragma unroll
            for (int j = 0; j < 8; j++)
                acc[i][j] += xm[i] * ln[j];
    }

    float ai[8], bj[8];
    #pragma unroll
    for (int i = 0; i < 4; i++) {
        ai[i] = As[4 * ty + i];
        ai[4 + i] = As[64 + 4 * ty + i];
    }
    #pragma unroll
    for (int j = 0; j < 4; j++) {
        bj[j] = Bs[4 * tx + j];
        bj[4 + j] = Bs[64 + 4 * tx + j];
    }

    #pragma unroll
    for (int i = 0; i < 8; i++) {
        int m = m0 + ((i < 4) ? (4 * ty + i) : (64 + 4 * ty + (i - 4)));
        f32x4 r0, r1;
        r0.x = __builtin_amdgcn_exp2f(acc[i][0] + (ai[i] + bj[0]));
        r0.y = __builtin_amdgcn_exp2f(acc[i][1] + (ai[i] + bj[1]));
        r0.z = __builtin_amdgcn_exp2f(acc[i][2] + (ai[i] + bj[2]));
        r0.w = __builtin_amdgcn_exp2f(acc[i][3] + (ai[i] + bj[3]));
        r1.x = __builtin_amdgcn_exp2f(acc[i][4] + (ai[i] + bj[4]));
        r1.y = __builtin_amdgcn_exp2f(acc[i][5] + (ai[i] + bj[5]));
        r1.z = __builtin_amdgcn_exp2f(acc[i][6] + (ai[i] + bj[6]));
        r1.w = __builtin_amdgcn_exp2f(acc[i][7] + (ai[i] + bj[7]));
        float* orow = out + (size_t)m * NROWS + n0;
        __builtin_nontemporal_store(r0, (f32x4*)&orow[4 * tx]);
        __builtin_nontemporal_store(r1, (f32x4*)&orow[64 + 4 * tx]);
    }
}

extern "C" void kernel_launch(void* const* d_in, const int* in_sizes, int n_in,
                              void* d_out, int out_size, void* d_ws, size_t ws_size,
                              hipStream_t stream) {
    const float* cent = (const float*)d_in[0];
    const float* x    = (const float*)d_in[1];
    const float* W1   = (const float*)d_in[2];
    const float* W2   = (const float*)d_in[3];
    const float* b2   = (const float*)d_in[4];
    float* out = (float*)d_out;

    float* ws  = (float*)d_ws;
    float* loc = ws;                    // 4096*32 floats (pre-scaled by log2e/var)
    float* A   = loc + NROWS * DIMS;    // 8192 floats
    float* B   = A + MROWS;             // 4096 floats

    k_prep<<<48, 256, 0, stream>>>(cent, x, W1, W2, b2, loc, A, B);
    k_pair<<<dim3(NROWS / TS, MROWS / TS), 256, 0, stream>>>(x, loc, A, B, out);
}